// Round 13
// baseline (503.476 us; speedup 1.0000x reference)
//
#include <hip/hip_runtime.h>

// LSTMClassifier: B=2048, T=500, H1=128, H2=64, D_IN=1, FC 64->128->4.
//
// Round 12 = R10 (511us best, absmax 2.44e-4) with control-flow shaved:
//  - Role-split scan loops: if(isL1) hoisted OUT of the 500-step loop; each
//    role runs a tight private loop. Barrier counts identical (501/wave,
//    same order) -> valid workgroup sync (wave-uniform branch).
//  - Parity unroll x2: cur/prv are compile-time literals (249 pairs + tail),
//    so every h-state ds_read/ds_write folds to base + const offset --
//    removes per-step address recomputation (~30 VALU/wave-step).
//  - Arithmetic bit-identical to R10 (same macros, same order, same cvt_pk).
// R11 falsified 2-blocks/CU: VGPR=84 -> 16-wave/CU HW cap, 24 waves never
// co-reside (occupancy stayed 35%, dur exactly 2x). R9 postmortem (via R10
// pass): permlane32_swap asm was the corruption -- avoided.
// Kept: 12 waves (8 L1 / 4 L2), skewed pipeline 1 barrier/step, parity
// buffers, fragment-native conflict-free LDS layouts (bank conflicts
// 2.87e7 -> 6.2e6), Whh2 in LDS, 7-trans cell (log2e pre-folded), setprio,
// 84-VGPR no-spill register shape.

#define B_   2048
#define T_   500
#define BM   8
#define NBLK (B_ / BM)   // 256 blocks = 1 per CU
#define NTHR 768         // 12 waves

typedef __attribute__((ext_vector_type(8))) short bf16x8;   // 8 bf16 = 4 VGPR
typedef __attribute__((ext_vector_type(4))) float f32x4;

#define LOG2E 1.44269504088896340736f

static __device__ __forceinline__ short f2bf(float f) {
  unsigned u = __builtin_bit_cast(unsigned, f);
  u = (u + 0x7fffu + ((u >> 16) & 1u)) >> 16;   // RNE (setup only)
  return (short)u;
}

// Gates pre-scaled by log2e. 5 exp2 + 2 rcp = 7 transcendentals, exact.
static __device__ __forceinline__ float lstm_cell_s(float gi, float gf, float gg,
                                                    float go, float& c) {
  float Ei = __builtin_amdgcn_exp2f(-gi);
  float Eg = __builtin_amdgcn_exp2f(gg + gg);
  float Ef = __builtin_amdgcn_exp2f(-gf);
  float Eo = __builtin_amdgcn_exp2f(-go);
  float t12 = (1.f + Ei) * (1.f + Eg);
  float num = c * t12 + (Eg - 1.f) * (1.f + Ef);
  c = num * __builtin_amdgcn_rcpf((1.f + Ef) * t12);
  float Ec = __builtin_amdgcn_exp2f(2.88539008177792681472f * c);  // 2*log2e*c
  return (Ec - 1.f) * __builtin_amdgcn_rcpf((1.f + Eo) * (1.f + Ec));
}

__global__ __launch_bounds__(NTHR)
void lstm_fused(const float* __restrict__ X,     // (B,1,T)
                const float* __restrict__ Wp,    // (128,1)
                const float* __restrict__ bp,    // (128)
                const float* __restrict__ Wih1,  // (512,128)
                const float* __restrict__ Whh1,  // (512,128)
                const float* __restrict__ bih1,  // (512)
                const float* __restrict__ bhh1,  // (512)
                const float* __restrict__ Wih2,  // (256,128)
                const float* __restrict__ Whh2,  // (256,64)
                const float* __restrict__ bih2,  // (256)
                const float* __restrict__ bhh2,  // (256)
                const float* __restrict__ W1,    // (128,64)
                const float* __restrict__ b1,    // (128)
                const float* __restrict__ W2,    // (4,128)
                const float* __restrict__ b2,    // (4)
                float* __restrict__ Out) {       // (B,4)
  // Fragment-native state: [buf][kf][slot=grp*16+row][e] holds
  // h[row][unit kf*32+grp*8+e]; read slot = lane ln is one lane-consecutive
  // b128. Slots grp*16+8..15 remain zero (pad rows).
  __shared__ __align__(16) short h1f[2][4][64][8];        // 8192 B
  __shared__ __align__(16) short h2g[2][2][64][8];        // 4096 B
  __shared__ __align__(16) short w2h[4][4][2][64][8];     // 32768 B Whh2 frags
  __shared__ __align__(16) float xsb[T_ * 8];             // 16000 B (fc1s aliases)
  __shared__ float h2f[8][64];                            // 2048 B -> 63104 B

  const int tid = threadIdx.x;
  const int ln = tid & 63;
  const int wv = tid >> 6;     // wave 0..11; 0-3 = LSTM2, 4-11 = LSTM1
  const int cl = ln & 15;      // fragment column (A row / unit-in-slice)
  const int kg = ln >> 4;      // K-group 0..3
  const int r0 = blockIdx.x * BM;
  const bool isL1 = (wv >= 4);
  const int w1 = wv - 4;       // LSTM1 wave index 0..7

  bf16x8 Wreg[4][4];           // shared slots: L1=Whh1 frags, L2=Wih2 frags
  float uv[8];  // L1: uv[0..3]=u1*log2e, uv[4..7]=v1*log2e. L2: uv[0..3]=bias.

  // ---------------- one-time setup (weights pre-scaled by log2e) ----------
  if (isL1) {
#pragma unroll
    for (int n = 0; n < 4; ++n) {
      const int R = n * 128 + 16 * w1 + cl;
      float u = 0.f, vv = bih1[R] + bhh1[R];
      const float4* Wi4 = (const float4*)(Wih1 + R * 128);
      const float4* Wp4 = (const float4*)Wp;
      const float4* bp4 = (const float4*)bp;
#pragma unroll 4
      for (int d = 0; d < 32; ++d) {
        float4 a = Wi4[d], pw = Wp4[d], qb = bp4[d];
        u  += a.x*pw.x + a.y*pw.y + a.z*pw.z + a.w*pw.w;
        vv += a.x*qb.x + a.y*qb.y + a.z*qb.z + a.w*qb.w;
      }
      uv[n] = u * LOG2E;
      uv[4 + n] = vv * LOG2E;
#pragma unroll
      for (int kf = 0; kf < 4; ++kf) {
        const float4* s4 = (const float4*)(Whh1 + R * 128 + kf * 32 + kg * 8);
        float4 a0 = s4[0], a1 = s4[1];
        bf16x8 fr;
        fr[0]=f2bf(a0.x*LOG2E); fr[1]=f2bf(a0.y*LOG2E);
        fr[2]=f2bf(a0.z*LOG2E); fr[3]=f2bf(a0.w*LOG2E);
        fr[4]=f2bf(a1.x*LOG2E); fr[5]=f2bf(a1.y*LOG2E);
        fr[6]=f2bf(a1.z*LOG2E); fr[7]=f2bf(a1.w*LOG2E);
        Wreg[n][kf] = fr;
      }
    }
  } else {
#pragma unroll
    for (int n = 0; n < 4; ++n) {
      const int R = n * 64 + 16 * wv + cl;
      uv[n] = (bih2[R] + bhh2[R]) * LOG2E;
#pragma unroll
      for (int kf = 0; kf < 4; ++kf) {
        const float4* s4 = (const float4*)(Wih2 + R * 128 + kf * 32 + kg * 8);
        float4 a0 = s4[0], a1 = s4[1];
        bf16x8 fr;
        fr[0]=f2bf(a0.x*LOG2E); fr[1]=f2bf(a0.y*LOG2E);
        fr[2]=f2bf(a0.z*LOG2E); fr[3]=f2bf(a0.w*LOG2E);
        fr[4]=f2bf(a1.x*LOG2E); fr[5]=f2bf(a1.y*LOG2E);
        fr[6]=f2bf(a1.z*LOG2E); fr[7]=f2bf(a1.w*LOG2E);
        Wreg[n][kf] = fr;
      }
      // Whh2 B-frags -> LDS (lane-consecutive 16B, conflict-free)
#pragma unroll
      for (int kf = 0; kf < 2; ++kf) {
        const float4* s4 = (const float4*)(Whh2 + R * 64 + kf * 32 + kg * 8);
        float4 a0 = s4[0], a1 = s4[1];
        short* dst = &w2h[wv][n][kf][ln][0];
        dst[0]=f2bf(a0.x*LOG2E); dst[1]=f2bf(a0.y*LOG2E);
        dst[2]=f2bf(a0.z*LOG2E); dst[3]=f2bf(a0.w*LOG2E);
        dst[4]=f2bf(a1.x*LOG2E); dst[5]=f2bf(a1.y*LOG2E);
        dst[6]=f2bf(a1.z*LOG2E); dst[7]=f2bf(a1.w*LOG2E);
      }
    }
  }

  // zero h-state dbufs (pad slots must stay zero); stage x rows 0..7
  for (int i = tid; i < 2 * 4 * 64 * 8; i += NTHR) ((short*)h1f)[i] = 0;
  for (int i = tid; i < 2 * 2 * 64 * 8; i += NTHR) ((short*)h2g)[i] = 0;
#pragma unroll
  for (int r = 0; r < 8; ++r)
    for (int t = tid; t < T_; t += NTHR)
      xsb[t * 8 + r] = X[(size_t)(r0 + r) * T_ + t];
  __syncthreads();

  // per-lane persistent state: every wave has exactly 2 cells (rA, rB).
  float c0 = 0.f, c1 = 0.f;
  const int rA = (kg < 2) ? kg * 4 : (kg - 2) * 4 + 2;   // redistributed rows
  const int rB = rA + 1;
  const int uu = 16 * (isL1 ? w1 : wv) + cl;             // owned unit
  // write slots: h[row][uu] -> [uu>>5][((uu>>3)&3)*16 + row][uu&7]
  const int wkf = uu >> 5, wg = ((uu >> 3) & 3) * 16, wel = uu & 7;
  const float xmask = (kg < 2) ? 1.f : 0.f;   // zero x on pad lanes (R8 sem.)

  // ======================= L1 step (h1(i) -> h1f[cur]) ====================
#define L1_STEP(i, cur, prv)                                                  \
  {                                                                           \
    bf16x8 a1[4];                                                             \
    _Pragma("unroll")                                                         \
    for (int kf = 0; kf < 4; ++kf)                                            \
      a1[kf] = *(const bf16x8*)&h1f[prv][kf][ln][0];                          \
    f32x4 xr4 = *(const f32x4*)&xsb[(i) * 8 + (kg & 1) * 4];                  \
    _Pragma("unroll")                                                         \
    for (int e = 0; e < 4; ++e) xr4[e] *= xmask;                              \
    f32x4 acc[4];                                                             \
    _Pragma("unroll")                                                         \
    for (int n = 0; n < 4; ++n) {                                             \
      _Pragma("unroll")                                                       \
      for (int e = 0; e < 4; ++e)                                             \
        acc[n][e] = xr4[e] * uv[n] + uv[4 + n];                               \
    }                                                                         \
    __builtin_amdgcn_s_setprio(1);                                            \
    _Pragma("unroll")                                                         \
    for (int n = 0; n < 4; ++n)                                               \
      _Pragma("unroll")                                                       \
      for (int kf = 0; kf < 4; ++kf)                                          \
        acc[n] = __builtin_amdgcn_mfma_f32_16x16x32_bf16(                     \
            a1[kf], Wreg[n][kf], acc[n], 0, 0, 0);                            \
    __builtin_amdgcn_s_setprio(0);                                            \
    float gA[4], gB[4];                                                       \
    _Pragma("unroll")                                                         \
    for (int n = 0; n < 4; ++n) {                                             \
      float s2 = __shfl_xor(acc[n][2], 32);                                   \
      float s3 = __shfl_xor(acc[n][3], 32);                                   \
      gA[n] = (kg < 2) ? acc[n][0] : s2;                                      \
      gB[n] = (kg < 2) ? acc[n][1] : s3;                                      \
    }                                                                         \
    float hA = lstm_cell_s(gA[0], gA[1], gA[2], gA[3], c0);                   \
    float hB = lstm_cell_s(gB[0], gB[1], gB[2], gB[3], c1);                   \
    unsigned pk;                                                              \
    asm("v_cvt_pk_bf16_f32 %0, %1, %2" : "=v"(pk) : "v"(hA), "v"(hB));        \
    h1f[cur][wkf][wg + rA][wel] = (short)pk;                                  \
    h1f[cur][wkf][wg + rB][wel] = (short)(pk >> 16);                          \
  }

  // ==== L2 step (h2(i-1): reads h1f[prv], h2g[cur] -> writes h2g[prv]) ====
#define L2_STEP(cur, prv, FINAL)                                              \
  {                                                                           \
    bf16x8 a1[4], ag[2];                                                      \
    _Pragma("unroll")                                                         \
    for (int kf = 0; kf < 4; ++kf)                                            \
      a1[kf] = *(const bf16x8*)&h1f[prv][kf][ln][0];                          \
    _Pragma("unroll")                                                         \
    for (int kf = 0; kf < 2; ++kf)                                            \
      ag[kf] = *(const bf16x8*)&h2g[cur][kf][ln][0];                          \
    f32x4 acc[4];                                                             \
    _Pragma("unroll")                                                         \
    for (int n = 0; n < 4; ++n)                                               \
      acc[n] = (f32x4){uv[n], uv[n], uv[n], uv[n]};                           \
    __builtin_amdgcn_s_setprio(1);                                            \
    _Pragma("unroll")                                                         \
    for (int n = 0; n < 4; ++n) {                                             \
      bf16x8 w0 = *(const bf16x8*)&w2h[wv][n][0][ln][0];                      \
      bf16x8 w1f = *(const bf16x8*)&w2h[wv][n][1][ln][0];                     \
      acc[n] = __builtin_amdgcn_mfma_f32_16x16x32_bf16(ag[0], w0,             \
                                                       acc[n], 0, 0, 0);      \
      acc[n] = __builtin_amdgcn_mfma_f32_16x16x32_bf16(ag[1], w1f,            \
                                                       acc[n], 0, 0, 0);      \
      _Pragma("unroll")                                                       \
      for (int kf = 0; kf < 4; ++kf)                                          \
        acc[n] = __builtin_amdgcn_mfma_f32_16x16x32_bf16(                     \
            a1[kf], Wreg[n][kf], acc[n], 0, 0, 0);                            \
    }                                                                         \
    __builtin_amdgcn_s_setprio(0);                                            \
    float gA[4], gB[4];                                                       \
    _Pragma("unroll")                                                         \
    for (int n = 0; n < 4; ++n) {                                             \
      float s2 = __shfl_xor(acc[n][2], 32);                                   \
      float s3 = __shfl_xor(acc[n][3], 32);                                   \
      gA[n] = (kg < 2) ? acc[n][0] : s2;                                      \
      gB[n] = (kg < 2) ? acc[n][1] : s3;                                      \
    }                                                                         \
    float hA = lstm_cell_s(gA[0], gA[1], gA[2], gA[3], c0);                   \
    float hB = lstm_cell_s(gB[0], gB[1], gB[2], gB[3], c1);                   \
    unsigned pk;                                                              \
    asm("v_cvt_pk_bf16_f32 %0, %1, %2" : "=v"(pk) : "v"(hA), "v"(hB));        \
    h2g[prv][wkf][wg + rA][wel] = (short)pk;                                  \
    h2g[prv][wkf][wg + rB][wel] = (short)(pk >> 16);                          \
    if (FINAL) { h2f[rA][uu] = hA; h2f[rB][uu] = hB; }                        \
  }

  // ---------------- the scan (role-split, parity-unrolled x2) -------------
  // Barrier schedule identical on both paths: 1 (prologue) + 498 (249 pairs)
  // + 1 (i=499) + 1 (epilogue) = 501 barriers per wave, same order.
  if (isL1) {
    L1_STEP(0, 0, 1);                 // prologue: h1(0)
    __syncthreads();
    int i = 1;
    for (int p = 0; p < 249; ++p) {   // pairs i=(1,2),(3,4),...,(497,498)
      L1_STEP(i, 1, 0);
      __syncthreads();
      L1_STEP(i + 1, 0, 1);
      __syncthreads();
      i += 2;
    }
    L1_STEP(499, 1, 0);               // tail i=499
    __syncthreads();
    __syncthreads();                  // epilogue barrier (L2 finishing)
  } else {
    __syncthreads();                  // prologue barrier (L1 computing h1(0))
    for (int p = 0; p < 249; ++p) {   // h2(0..497) in pairs
      L2_STEP(1, 0, 0);
      __syncthreads();
      L2_STEP(0, 1, 0);
      __syncthreads();
    }
    L2_STEP(1, 0, 0);                 // h2(498)
    __syncthreads();
    L2_STEP(0, 1, 1);                 // epilogue: h2(499)
    __syncthreads();
  }

  // ---------------- FC head (fp32); fc1s aliases dead xsb ----------------
  float* fc1s = xsb;                 // [8][132] layout inside 4000 floats
  if (tid < 512) {
    const int u = tid & 127, r2 = tid >> 7;   // r2 0..3 -> rows 2r2, 2r2+1
    float a0 = b1[u], a1f = b1[u];
    for (int k = 0; k < 64; ++k) {
      float w = W1[u * 64 + k];
      a0  += h2f[r2 * 2 + 0][k] * w;
      a1f += h2f[r2 * 2 + 1][k] * w;
    }
    fc1s[(r2 * 2 + 0) * 132 + u] = fmaxf(a0, 0.f);
    fc1s[(r2 * 2 + 1) * 132 + u] = fmaxf(a1f, 0.f);
  }
  __syncthreads();
  if (tid < 32) {
    const int r = tid >> 2, cls = tid & 3;
    float a = b2[cls];
    for (int k = 0; k < 128; ++k) a += fc1s[r * 132 + k] * W2[cls * 128 + k];
    Out[(size_t)(r0 + r) * 4 + cls] = a;
  }
}

extern "C" void kernel_launch(void* const* d_in, const int* in_sizes, int n_in,
                              void* d_out, int out_size, void* d_ws, size_t ws_size,
                              hipStream_t stream) {
  const float* X    = (const float*)d_in[0];
  const float* Wp   = (const float*)d_in[1];
  const float* bp   = (const float*)d_in[2];
  const float* Wih1 = (const float*)d_in[3];
  const float* Whh1 = (const float*)d_in[4];
  const float* bih1 = (const float*)d_in[5];
  const float* bhh1 = (const float*)d_in[6];
  const float* Wih2 = (const float*)d_in[7];
  const float* Whh2 = (const float*)d_in[8];
  const float* bih2 = (const float*)d_in[9];
  const float* bhh2 = (const float*)d_in[10];
  const float* W1   = (const float*)d_in[11];
  const float* b1   = (const float*)d_in[12];
  const float* W2   = (const float*)d_in[13];
  const float* b2   = (const float*)d_in[14];
  float* Out = (float*)d_out;

  hipLaunchKernelGGL(lstm_fused, dim3(NBLK), dim3(NTHR), 0, stream,
                     X, Wp, bp, Wih1, Whh1, bih1, bhh1,
                     Wih2, Whh2, bih2, bhh2, W1, b1, W2, b2, Out);
}

// Round 14
// 459.890 us; speedup vs baseline: 1.0948x; 1.0948x over previous
//
#include <hip/hip_runtime.h>

// LSTMClassifier: B=2048, T=500, H1=128, H2=64, D_IN=1, FC 64->128->4.
//
// Round 14 = R13 (503us, absmax 2.44e-4) with the gate redistribution moved
// OFF the LDS pipe. Pipe model from R13 counters: ~216 LDS ops/step/CU
// (h-frag b128 reads + x + w2h + writes + 96 __shfl_xor ds_swizzles) at
// ~6-12 cyc each ~= 2000 cyc of the 2780-cyc step -> LDS op COUNT is the
// binding resource (not conflicts: 6.2e6; not VALU: 43%).
// Change (single variable): __shfl_xor(.,32)+select -> 
// __builtin_amdgcn_permlane32_swap (VALU, gfx950; T12/m214-proven BUILTIN --
// R9's raw-asm form corrupted, the builtin gets proper hazard handling).
// permlane32_swap(d,s).x = {lanes 0-31: d(own), lanes 32-63: s from lane-32}
// == gA/gB including the select -> 8 shfl + 8 cndmask become 8 VALU swaps.
// LDS ops 216 -> 120/step. Everything else bit-identical to R13; absmax
// must stay exactly 2.441406e-04 (canary isolates the primitive).
// Kept: 12 waves (8 L1 / 4 L2), skewed pipeline 1 barrier/step, role-split
// parity-unrolled scan, fragment-native conflict-free LDS layouts, Whh2 in
// LDS, 7-trans cell (log2e pre-folded), setprio, 84-VGPR no-spill shape.

#define B_   2048
#define T_   500
#define BM   8
#define NBLK (B_ / BM)   // 256 blocks = 1 per CU
#define NTHR 768         // 12 waves

typedef __attribute__((ext_vector_type(8))) short bf16x8;   // 8 bf16 = 4 VGPR
typedef __attribute__((ext_vector_type(4))) float f32x4;

#define LOG2E 1.44269504088896340736f

static __device__ __forceinline__ short f2bf(float f) {
  unsigned u = __builtin_bit_cast(unsigned, f);
  u = (u + 0x7fffu + ((u >> 16) & 1u)) >> 16;   // RNE (setup only)
  return (short)u;
}

// Gates pre-scaled by log2e. 5 exp2 + 2 rcp = 7 transcendentals, exact.
static __device__ __forceinline__ float lstm_cell_s(float gi, float gf, float gg,
                                                    float go, float& c) {
  float Ei = __builtin_amdgcn_exp2f(-gi);
  float Eg = __builtin_amdgcn_exp2f(gg + gg);
  float Ef = __builtin_amdgcn_exp2f(-gf);
  float Eo = __builtin_amdgcn_exp2f(-go);
  float t12 = (1.f + Ei) * (1.f + Eg);
  float num = c * t12 + (Eg - 1.f) * (1.f + Ef);
  c = num * __builtin_amdgcn_rcpf((1.f + Ef) * t12);
  float Ec = __builtin_amdgcn_exp2f(2.88539008177792681472f * c);  // 2*log2e*c
  return (Ec - 1.f) * __builtin_amdgcn_rcpf((1.f + Eo) * (1.f + Ec));
}

// gdst = {lanes 0-31: d (own lane), lanes 32-63: s from lane-32}.
// VALU permlane (no LDS pipe). Fallback: R13's shfl_xor+select (LDS pipe).
#if __has_builtin(__builtin_amdgcn_permlane32_swap)
#define GSWAP(gdst, d, s)                                                     \
  {                                                                           \
    auto _r = __builtin_amdgcn_permlane32_swap(                               \
        __builtin_bit_cast(unsigned, (d)), __builtin_bit_cast(unsigned, (s)), \
        false, false);                                                        \
    gdst = __builtin_bit_cast(float, _r[0]);                                  \
  }
#else
#define GSWAP(gdst, d, s)                                                     \
  {                                                                           \
    float _s2 = __shfl_xor((s), 32);                                          \
    gdst = (kg < 2) ? (d) : _s2;                                              \
  }
#endif

__global__ __launch_bounds__(NTHR)
void lstm_fused(const float* __restrict__ X,     // (B,1,T)
                const float* __restrict__ Wp,    // (128,1)
                const float* __restrict__ bp,    // (128)
                const float* __restrict__ Wih1,  // (512,128)
                const float* __restrict__ Whh1,  // (512,128)
                const float* __restrict__ bih1,  // (512)
                const float* __restrict__ bhh1,  // (512)
                const float* __restrict__ Wih2,  // (256,128)
                const float* __restrict__ Whh2,  // (256,64)
                const float* __restrict__ bih2,  // (256)
                const float* __restrict__ bhh2,  // (256)
                const float* __restrict__ W1,    // (128,64)
                const float* __restrict__ b1,    // (128)
                const float* __restrict__ W2,    // (4,128)
                const float* __restrict__ b2,    // (4)
                float* __restrict__ Out) {       // (B,4)
  // Fragment-native state: [buf][kf][slot=grp*16+row][e] holds
  // h[row][unit kf*32+grp*8+e]; read slot = lane ln is one lane-consecutive
  // b128. Slots grp*16+8..15 remain zero (pad rows).
  __shared__ __align__(16) short h1f[2][4][64][8];        // 8192 B
  __shared__ __align__(16) short h2g[2][2][64][8];        // 4096 B
  __shared__ __align__(16) short w2h[4][4][2][64][8];     // 32768 B Whh2 frags
  __shared__ __align__(16) float xsb[T_ * 8];             // 16000 B (fc1s aliases)
  __shared__ float h2f[8][64];                            // 2048 B -> 63104 B

  const int tid = threadIdx.x;
  const int ln = tid & 63;
  const int wv = tid >> 6;     // wave 0..11; 0-3 = LSTM2, 4-11 = LSTM1
  const int cl = ln & 15;      // fragment column (A row / unit-in-slice)
  const int kg = ln >> 4;      // K-group 0..3
  const int r0 = blockIdx.x * BM;
  const bool isL1 = (wv >= 4);
  const int w1 = wv - 4;       // LSTM1 wave index 0..7

  bf16x8 Wreg[4][4];           // shared slots: L1=Whh1 frags, L2=Wih2 frags
  float uv[8];  // L1: uv[0..3]=u1*log2e, uv[4..7]=v1*log2e. L2: uv[0..3]=bias.

  // ---------------- one-time setup (weights pre-scaled by log2e) ----------
  if (isL1) {
#pragma unroll
    for (int n = 0; n < 4; ++n) {
      const int R = n * 128 + 16 * w1 + cl;
      float u = 0.f, vv = bih1[R] + bhh1[R];
      const float4* Wi4 = (const float4*)(Wih1 + R * 128);
      const float4* Wp4 = (const float4*)Wp;
      const float4* bp4 = (const float4*)bp;
#pragma unroll 4
      for (int d = 0; d < 32; ++d) {
        float4 a = Wi4[d], pw = Wp4[d], qb = bp4[d];
        u  += a.x*pw.x + a.y*pw.y + a.z*pw.z + a.w*pw.w;
        vv += a.x*qb.x + a.y*qb.y + a.z*qb.z + a.w*qb.w;
      }
      uv[n] = u * LOG2E;
      uv[4 + n] = vv * LOG2E;
#pragma unroll
      for (int kf = 0; kf < 4; ++kf) {
        const float4* s4 = (const float4*)(Whh1 + R * 128 + kf * 32 + kg * 8);
        float4 a0 = s4[0], a1 = s4[1];
        bf16x8 fr;
        fr[0]=f2bf(a0.x*LOG2E); fr[1]=f2bf(a0.y*LOG2E);
        fr[2]=f2bf(a0.z*LOG2E); fr[3]=f2bf(a0.w*LOG2E);
        fr[4]=f2bf(a1.x*LOG2E); fr[5]=f2bf(a1.y*LOG2E);
        fr[6]=f2bf(a1.z*LOG2E); fr[7]=f2bf(a1.w*LOG2E);
        Wreg[n][kf] = fr;
      }
    }
  } else {
#pragma unroll
    for (int n = 0; n < 4; ++n) {
      const int R = n * 64 + 16 * wv + cl;
      uv[n] = (bih2[R] + bhh2[R]) * LOG2E;
#pragma unroll
      for (int kf = 0; kf < 4; ++kf) {
        const float4* s4 = (const float4*)(Wih2 + R * 128 + kf * 32 + kg * 8);
        float4 a0 = s4[0], a1 = s4[1];
        bf16x8 fr;
        fr[0]=f2bf(a0.x*LOG2E); fr[1]=f2bf(a0.y*LOG2E);
        fr[2]=f2bf(a0.z*LOG2E); fr[3]=f2bf(a0.w*LOG2E);
        fr[4]=f2bf(a1.x*LOG2E); fr[5]=f2bf(a1.y*LOG2E);
        fr[6]=f2bf(a1.z*LOG2E); fr[7]=f2bf(a1.w*LOG2E);
        Wreg[n][kf] = fr;
      }
      // Whh2 B-frags -> LDS (lane-consecutive 16B, conflict-free)
#pragma unroll
      for (int kf = 0; kf < 2; ++kf) {
        const float4* s4 = (const float4*)(Whh2 + R * 64 + kf * 32 + kg * 8);
        float4 a0 = s4[0], a1 = s4[1];
        short* dst = &w2h[wv][n][kf][ln][0];
        dst[0]=f2bf(a0.x*LOG2E); dst[1]=f2bf(a0.y*LOG2E);
        dst[2]=f2bf(a0.z*LOG2E); dst[3]=f2bf(a0.w*LOG2E);
        dst[4]=f2bf(a1.x*LOG2E); dst[5]=f2bf(a1.y*LOG2E);
        dst[6]=f2bf(a1.z*LOG2E); dst[7]=f2bf(a1.w*LOG2E);
      }
    }
  }

  // zero h-state dbufs (pad slots must stay zero); stage x rows 0..7
  for (int i = tid; i < 2 * 4 * 64 * 8; i += NTHR) ((short*)h1f)[i] = 0;
  for (int i = tid; i < 2 * 2 * 64 * 8; i += NTHR) ((short*)h2g)[i] = 0;
#pragma unroll
  for (int r = 0; r < 8; ++r)
    for (int t = tid; t < T_; t += NTHR)
      xsb[t * 8 + r] = X[(size_t)(r0 + r) * T_ + t];
  __syncthreads();

  // per-lane persistent state: every wave has exactly 2 cells (rA, rB).
  float c0 = 0.f, c1 = 0.f;
  const int rA = (kg < 2) ? kg * 4 : (kg - 2) * 4 + 2;   // redistributed rows
  const int rB = rA + 1;
  const int uu = 16 * (isL1 ? w1 : wv) + cl;             // owned unit
  // write slots: h[row][uu] -> [uu>>5][((uu>>3)&3)*16 + row][uu&7]
  const int wkf = uu >> 5, wg = ((uu >> 3) & 3) * 16, wel = uu & 7;
  const float xmask = (kg < 2) ? 1.f : 0.f;   // zero x on pad lanes (R8 sem.)

  // ======================= L1 step (h1(i) -> h1f[cur]) ====================
#define L1_STEP(i, cur, prv)                                                  \
  {                                                                           \
    bf16x8 a1[4];                                                             \
    _Pragma("unroll")                                                         \
    for (int kf = 0; kf < 4; ++kf)                                            \
      a1[kf] = *(const bf16x8*)&h1f[prv][kf][ln][0];                          \
    f32x4 xr4 = *(const f32x4*)&xsb[(i) * 8 + (kg & 1) * 4];                  \
    _Pragma("unroll")                                                         \
    for (int e = 0; e < 4; ++e) xr4[e] *= xmask;                              \
    f32x4 acc[4];                                                             \
    _Pragma("unroll")                                                         \
    for (int n = 0; n < 4; ++n) {                                             \
      _Pragma("unroll")                                                       \
      for (int e = 0; e < 4; ++e)                                             \
        acc[n][e] = xr4[e] * uv[n] + uv[4 + n];                               \
    }                                                                         \
    __builtin_amdgcn_s_setprio(1);                                            \
    _Pragma("unroll")                                                         \
    for (int n = 0; n < 4; ++n)                                               \
      _Pragma("unroll")                                                       \
      for (int kf = 0; kf < 4; ++kf)                                          \
        acc[n] = __builtin_amdgcn_mfma_f32_16x16x32_bf16(                     \
            a1[kf], Wreg[n][kf], acc[n], 0, 0, 0);                            \
    __builtin_amdgcn_s_setprio(0);                                            \
    float gA[4], gB[4];                                                       \
    _Pragma("unroll")                                                         \
    for (int n = 0; n < 4; ++n) {                                             \
      GSWAP(gA[n], acc[n][0], acc[n][2]);                                     \
      GSWAP(gB[n], acc[n][1], acc[n][3]);                                     \
    }                                                                         \
    float hA = lstm_cell_s(gA[0], gA[1], gA[2], gA[3], c0);                   \
    float hB = lstm_cell_s(gB[0], gB[1], gB[2], gB[3], c1);                   \
    unsigned pk;                                                              \
    asm("v_cvt_pk_bf16_f32 %0, %1, %2" : "=v"(pk) : "v"(hA), "v"(hB));        \
    h1f[cur][wkf][wg + rA][wel] = (short)pk;                                  \
    h1f[cur][wkf][wg + rB][wel] = (short)(pk >> 16);                          \
  }

  // ==== L2 step (h2(i-1): reads h1f[prv], h2g[cur] -> writes h2g[prv]) ====
#define L2_STEP(cur, prv, FINAL)                                              \
  {                                                                           \
    bf16x8 a1[4], ag[2];                                                      \
    _Pragma("unroll")                                                         \
    for (int kf = 0; kf < 4; ++kf)                                            \
      a1[kf] = *(const bf16x8*)&h1f[prv][kf][ln][0];                          \
    _Pragma("unroll")                                                         \
    for (int kf = 0; kf < 2; ++kf)                                            \
      ag[kf] = *(const bf16x8*)&h2g[cur][kf][ln][0];                          \
    f32x4 acc[4];                                                             \
    _Pragma("unroll")                                                         \
    for (int n = 0; n < 4; ++n)                                               \
      acc[n] = (f32x4){uv[n], uv[n], uv[n], uv[n]};                           \
    __builtin_amdgcn_s_setprio(1);                                            \
    _Pragma("unroll")                                                         \
    for (int n = 0; n < 4; ++n) {                                             \
      bf16x8 w0 = *(const bf16x8*)&w2h[wv][n][0][ln][0];                      \
      bf16x8 w1f = *(const bf16x8*)&w2h[wv][n][1][ln][0];                     \
      acc[n] = __builtin_amdgcn_mfma_f32_16x16x32_bf16(ag[0], w0,             \
                                                       acc[n], 0, 0, 0);      \
      acc[n] = __builtin_amdgcn_mfma_f32_16x16x32_bf16(ag[1], w1f,            \
                                                       acc[n], 0, 0, 0);      \
      _Pragma("unroll")                                                       \
      for (int kf = 0; kf < 4; ++kf)                                          \
        acc[n] = __builtin_amdgcn_mfma_f32_16x16x32_bf16(                     \
            a1[kf], Wreg[n][kf], acc[n], 0, 0, 0);                            \
    }                                                                         \
    __builtin_amdgcn_s_setprio(0);                                            \
    float gA[4], gB[4];                                                       \
    _Pragma("unroll")                                                         \
    for (int n = 0; n < 4; ++n) {                                             \
      GSWAP(gA[n], acc[n][0], acc[n][2]);                                     \
      GSWAP(gB[n], acc[n][1], acc[n][3]);                                     \
    }                                                                         \
    float hA = lstm_cell_s(gA[0], gA[1], gA[2], gA[3], c0);                   \
    float hB = lstm_cell_s(gB[0], gB[1], gB[2], gB[3], c1);                   \
    unsigned pk;                                                              \
    asm("v_cvt_pk_bf16_f32 %0, %1, %2" : "=v"(pk) : "v"(hA), "v"(hB));        \
    h2g[prv][wkf][wg + rA][wel] = (short)pk;                                  \
    h2g[prv][wkf][wg + rB][wel] = (short)(pk >> 16);                          \
    if (FINAL) { h2f[rA][uu] = hA; h2f[rB][uu] = hB; }                        \
  }

  // ---------------- the scan (role-split, parity-unrolled x2) -------------
  // Barrier schedule identical on both paths: 501 barriers/wave, same order.
  if (isL1) {
    L1_STEP(0, 0, 1);                 // prologue: h1(0)
    __syncthreads();
    int i = 1;
    for (int p = 0; p < 249; ++p) {   // pairs i=(1,2),(3,4),...,(497,498)
      L1_STEP(i, 1, 0);
      __syncthreads();
      L1_STEP(i + 1, 0, 1);
      __syncthreads();
      i += 2;
    }
    L1_STEP(499, 1, 0);               // tail i=499
    __syncthreads();
    __syncthreads();                  // epilogue barrier (L2 finishing)
  } else {
    __syncthreads();                  // prologue barrier (L1 computing h1(0))
    for (int p = 0; p < 249; ++p) {   // h2(0..497) in pairs
      L2_STEP(1, 0, 0);
      __syncthreads();
      L2_STEP(0, 1, 0);
      __syncthreads();
    }
    L2_STEP(1, 0, 0);                 // h2(498)
    __syncthreads();
    L2_STEP(0, 1, 1);                 // epilogue: h2(499)
    __syncthreads();
  }

  // ---------------- FC head (fp32); fc1s aliases dead xsb ----------------
  float* fc1s = xsb;                 // [8][132] layout inside 4000 floats
  if (tid < 512) {
    const int u = tid & 127, r2 = tid >> 7;   // r2 0..3 -> rows 2r2, 2r2+1
    float a0 = b1[u], a1f = b1[u];
    for (int k = 0; k < 64; ++k) {
      float w = W1[u * 64 + k];
      a0  += h2f[r2 * 2 + 0][k] * w;
      a1f += h2f[r2 * 2 + 1][k] * w;
    }
    fc1s[(r2 * 2 + 0) * 132 + u] = fmaxf(a0, 0.f);
    fc1s[(r2 * 2 + 1) * 132 + u] = fmaxf(a1f, 0.f);
  }
  __syncthreads();
  if (tid < 32) {
    const int r = tid >> 2, cls = tid & 3;
    float a = b2[cls];
    for (int k = 0; k < 128; ++k) a += fc1s[r * 132 + k] * W2[cls * 128 + k];
    Out[(size_t)(r0 + r) * 4 + cls] = a;
  }
}

extern "C" void kernel_launch(void* const* d_in, const int* in_sizes, int n_in,
                              void* d_out, int out_size, void* d_ws, size_t ws_size,
                              hipStream_t stream) {
  const float* X    = (const float*)d_in[0];
  const float* Wp   = (const float*)d_in[1];
  const float* bp   = (const float*)d_in[2];
  const float* Wih1 = (const float*)d_in[3];
  const float* Whh1 = (const float*)d_in[4];
  const float* bih1 = (const float*)d_in[5];
  const float* bhh1 = (const float*)d_in[6];
  const float* Wih2 = (const float*)d_in[7];
  const float* Whh2 = (const float*)d_in[8];
  const float* bih2 = (const float*)d_in[9];
  const float* bhh2 = (const float*)d_in[10];
  const float* W1   = (const float*)d_in[11];
  const float* b1   = (const float*)d_in[12];
  const float* W2   = (const float*)d_in[13];
  const float* b2   = (const float*)d_in[14];
  float* Out = (float*)d_out;

  hipLaunchKernelGGL(lstm_fused, dim3(NBLK), dim3(NTHR), 0, stream,
                     X, Wp, bp, Wih1, Whh1, bih1, bhh1,
                     Wih2, Whh2, bih2, bhh2, W1, b1, W2, b2, Out);
}